// Round 6
// baseline (3222.005 us; speedup 1.0000x reference)
//
#include <hip/hip_runtime.h>
#include <hip/hip_bf16.h>
#include <math.h>

constexpr int kB    = 64;
constexpr int kN    = 36;
constexpr int kBN   = kB * kN;   // 2304
constexpr int kD    = 2048;
constexpr int kDatt = 512;
constexpr int kPairs = kN * kN;  // 1296

using bf16x8 = __attribute__((ext_vector_type(8))) short;
using f32x4  = __attribute__((ext_vector_type(4))) float;

typedef unsigned int u32;
typedef __attribute__((address_space(3))) u32 lds_u32;
typedef const __attribute__((address_space(1))) u32 glb_u32;

__device__ inline unsigned short f2bf(float f) {
    union { float f; unsigned u; } v; v.f = f;
    unsigned r = v.u + 0x7FFFu + ((v.u >> 16) & 1u);   // RNE
    return (unsigned short)(r >> 16);
}

// ---------------------------------------------------------------------------
// kcvt: f32 -> bf16 elementwise
// ---------------------------------------------------------------------------
__global__ __launch_bounds__(256)
void kcvt(const float* __restrict__ x, unsigned short* __restrict__ y, int n4)
{
    int i = blockIdx.x * 256 + threadIdx.x;
    if (i < n4) {
        float4 v = ((const float4*)x)[i];
        ushort4 o = {f2bf(v.x), f2bf(v.y), f2bf(v.z), f2bf(v.w)};
        ((ushort4*)y)[i] = o;
    }
}

// ---------------------------------------------------------------------------
// ktrp: W[kD][nt] f32 -> WT[nt][kD] bf16 (transpose + convert)
// ---------------------------------------------------------------------------
__global__ __launch_bounds__(256)
void ktrp(const float* __restrict__ W, unsigned short* __restrict__ WT, int nt)
{
    __shared__ float T[64][65];
    const int k0 = blockIdx.x * 64;
    const int n0 = blockIdx.y * 64;
    const int c = threadIdx.x & 63, r0 = threadIdx.x >> 6;
    #pragma unroll
    for (int rr = 0; rr < 64; rr += 4)
        T[r0 + rr][c] = W[(size_t)(k0 + r0 + rr) * nt + n0 + c];
    __syncthreads();
    #pragma unroll
    for (int rr = 0; rr < 64; rr += 4)
        WT[(size_t)(n0 + r0 + rr) * kD + k0 + c] = f2bf(T[c][r0 + rr]);
}

// ---------------------------------------------------------------------------
// K3: ba/bb = box @ Wba/Wbb, K=4 -> elementwise
// ---------------------------------------------------------------------------
__global__ __launch_bounds__(256)
void k3_box_proj(const float* __restrict__ box, const float* __restrict__ Wba,
                 const float* __restrict__ Wbb,
                 float* __restrict__ ba, float* __restrict__ bb)
{
    const int r = blockIdx.y;
    const int c = blockIdx.x * 256 + threadIdx.x;
    const float x0 = box[r * 4 + 0], x1 = box[r * 4 + 1];
    const float x2 = box[r * 4 + 2], x3 = box[r * 4 + 3];
    float va = x0 * Wba[c] + x1 * Wba[kD + c] + x2 * Wba[2 * kD + c] + x3 * Wba[3 * kD + c];
    float vb = x0 * Wbb[c] + x1 * Wbb[kD + c] + x2 * Wbb[2 * kD + c] + x3 * Wbb[3 * kD + c];
    ba[(size_t)r * kD + c] = va;
    bb[(size_t)r * kD + c] = vb;
}

// ---------------------------------------------------------------------------
// Staging helpers for k1/k2: Rx32 bf16 tiles via global_load_lds width=16.
// ---------------------------------------------------------------------------
__device__ inline void stage128(const unsigned short* __restrict__ g,
                                int grow0, int k0,
                                unsigned short* lds, int w, int lane)
{
    const int sr = lane >> 2, sc = (lane & 3) * 8;
    #pragma unroll
    for (int t = 0; t < 2; ++t) {
        int r = w * 32 + t * 16;
        const unsigned short* gp = g + (size_t)(grow0 + r + sr) * kD + k0 + sc;
        __builtin_amdgcn_global_load_lds((glb_u32*)gp, (lds_u32*)(lds + r * 32), 16, 0, 0);
    }
}
__device__ inline void stage64(const unsigned short* __restrict__ g,
                               int grow0, int k0,
                               unsigned short* lds, int w, int lane)
{
    const int sr = lane >> 2, sc = (lane & 3) * 8;
    int r = w * 16;
    const unsigned short* gp = g + (size_t)(grow0 + r + sr) * kD + k0 + sc;
    __builtin_amdgcn_global_load_lds((glb_u32*)gp, (lds_u32*)(lds + r * 32), 16, 0, 0);
}

// ---------------------------------------------------------------------------
// K1 (MFMA dual): fused_bf16 = bf16((Qb @ WqT') .* (Ob @ WoT')), 128x64 tile
// ---------------------------------------------------------------------------
__global__ __launch_bounds__(256, 2)
void k1_dual_mfma(const unsigned short* __restrict__ Qb,
                  const unsigned short* __restrict__ WqT,
                  const unsigned short* __restrict__ Ob,
                  const unsigned short* __restrict__ WoT,
                  unsigned short* __restrict__ fusedb)
{
    __shared__ __align__(16) unsigned short As1[128][32];
    __shared__ __align__(16) unsigned short As2[128][32];
    __shared__ __align__(16) unsigned short Bs1[64][32];
    __shared__ __align__(16) unsigned short Bs2[64][32];

    const int tid = threadIdx.x;
    const int lane = tid & 63;
    const int w = tid >> 6;
    const int wm = w >> 1, wn = w & 1;
    const int row0 = blockIdx.y * 128;
    const int col0 = blockIdx.x * 64;

    f32x4 acc1[4][2], acc2[4][2];
    #pragma unroll
    for (int mt = 0; mt < 4; ++mt)
        #pragma unroll
        for (int nt = 0; nt < 2; ++nt) { acc1[mt][nt] = (f32x4)(0.f); acc2[mt][nt] = (f32x4)(0.f); }

    const int fr = lane & 15, ko = (lane >> 4) * 8;

    for (int k0 = 0; k0 < kD; k0 += 32) {
        stage128(Qb,  row0, k0, &As1[0][0], w, lane);
        stage128(Ob,  row0, k0, &As2[0][0], w, lane);
        stage64 (WqT, col0, k0, &Bs1[0][0], w, lane);
        stage64 (WoT, col0, k0, &Bs2[0][0], w, lane);
        __syncthreads();

        bf16x8 a1[4], a2[4];
        #pragma unroll
        for (int mt = 0; mt < 4; ++mt) {
            a1[mt] = *(bf16x8*)&As1[wm * 64 + mt * 16 + fr][ko];
            a2[mt] = *(bf16x8*)&As2[wm * 64 + mt * 16 + fr][ko];
        }
        #pragma unroll
        for (int nt = 0; nt < 2; ++nt) {
            bf16x8 b1 = *(bf16x8*)&Bs1[wn * 32 + nt * 16 + fr][ko];
            bf16x8 b2 = *(bf16x8*)&Bs2[wn * 32 + nt * 16 + fr][ko];
            #pragma unroll
            for (int mt = 0; mt < 4; ++mt) {
                acc1[mt][nt] = __builtin_amdgcn_mfma_f32_16x16x32_bf16(a1[mt], b1, acc1[mt][nt], 0, 0, 0);
                acc2[mt][nt] = __builtin_amdgcn_mfma_f32_16x16x32_bf16(a2[mt], b2, acc2[mt][nt], 0, 0, 0);
            }
        }
        __syncthreads();
    }

    const int fq = lane >> 4;
    #pragma unroll
    for (int mt = 0; mt < 4; ++mt)
        #pragma unroll
        for (int nt = 0; nt < 2; ++nt) {
            int row = row0 + wm * 64 + mt * 16 + fq * 4;
            int col = col0 + wn * 32 + nt * 16 + fr;
            #pragma unroll
            for (int reg = 0; reg < 4; ++reg) {
                float v = acc1[mt][nt][reg] * acc2[mt][nt][reg];
                fusedb[(size_t)(row + reg) * kD + col] = f2bf(v);
            }
        }
}

// ---------------------------------------------------------------------------
// K2 (MFMA dual-B): ra = Fb @ WfaT', rb = Fb @ WfbT', 128x64 tile
// ---------------------------------------------------------------------------
__global__ __launch_bounds__(256, 2)
void k2_dual_mfma(const unsigned short* __restrict__ Fb,
                  const unsigned short* __restrict__ WfaT,
                  const unsigned short* __restrict__ WfbT,
                  float* __restrict__ ra, float* __restrict__ rb)
{
    __shared__ __align__(16) unsigned short As [128][32];
    __shared__ __align__(16) unsigned short Bs1[64][32];
    __shared__ __align__(16) unsigned short Bs2[64][32];

    const int tid = threadIdx.x;
    const int lane = tid & 63;
    const int w = tid >> 6;
    const int wm = w >> 1, wn = w & 1;
    const int row0 = blockIdx.y * 128;
    const int col0 = blockIdx.x * 64;

    f32x4 acc1[4][2], acc2[4][2];
    #pragma unroll
    for (int mt = 0; mt < 4; ++mt)
        #pragma unroll
        for (int nt = 0; nt < 2; ++nt) { acc1[mt][nt] = (f32x4)(0.f); acc2[mt][nt] = (f32x4)(0.f); }

    const int fr = lane & 15, ko = (lane >> 4) * 8;

    for (int k0 = 0; k0 < kD; k0 += 32) {
        stage128(Fb,   row0, k0, &As [0][0], w, lane);
        stage64 (WfaT, col0, k0, &Bs1[0][0], w, lane);
        stage64 (WfbT, col0, k0, &Bs2[0][0], w, lane);
        __syncthreads();

        bf16x8 a[4];
        #pragma unroll
        for (int mt = 0; mt < 4; ++mt)
            a[mt] = *(bf16x8*)&As[wm * 64 + mt * 16 + fr][ko];
        #pragma unroll
        for (int nt = 0; nt < 2; ++nt) {
            bf16x8 b1 = *(bf16x8*)&Bs1[wn * 32 + nt * 16 + fr][ko];
            bf16x8 b2 = *(bf16x8*)&Bs2[wn * 32 + nt * 16 + fr][ko];
            #pragma unroll
            for (int mt = 0; mt < 4; ++mt) {
                acc1[mt][nt] = __builtin_amdgcn_mfma_f32_16x16x32_bf16(a[mt], b1, acc1[mt][nt], 0, 0, 0);
                acc2[mt][nt] = __builtin_amdgcn_mfma_f32_16x16x32_bf16(a[mt], b2, acc2[mt][nt], 0, 0, 0);
            }
        }
        __syncthreads();
    }

    const int fq = lane >> 4;
    #pragma unroll
    for (int mt = 0; mt < 4; ++mt)
        #pragma unroll
        for (int nt = 0; nt < 2; ++nt) {
            int row = row0 + wm * 64 + mt * 16 + fq * 4;
            int col = col0 + wn * 32 + nt * 16 + fr;
            #pragma unroll
            for (int reg = 0; reg < 4; ++reg) {
                size_t o = (size_t)(row + reg) * kD + col;
                ra[o] = acc1[mt][nt][reg];
                rb[o] = acc2[mt][nt][reg];
            }
        }
}

// ---------------------------------------------------------------------------
// K4 v4: 2 blocks/CU. LDS = Bs double (64K) + RelS single (10K) = 76.3K.
// Two barriers per K-step; DMA + A-loads issued AFTER B2 so they fly
// through the whole MFMA phase and are already complete at next B1's
// vmcnt(0). RelS single-buffer is safe: lgkmcnt(0) at B1 guarantees all
// af ds_reads completed before any wave overwrites RelS.
// ---------------------------------------------------------------------------
__global__ __launch_bounds__(512, 4)
void k4_scores_mfma(const float* __restrict__ ra, const float* __restrict__ rb,
                    const float* __restrict__ ba, const float* __restrict__ bb,
                    const unsigned short* __restrict__ W0T,
                    const float* __restrict__ b0, const float* __restrict__ W1,
                    float* __restrict__ scores)
{
    __shared__ __align__(16) unsigned short Bs[2][512][32];   // 64 KB
    __shared__ __align__(16) unsigned short RelS[128][40];    // 10 KB
    __shared__ float scoreS[128];

    const int tid  = threadIdx.x;
    const int lane = tid & 63;
    const int w    = tid >> 6;        // 0..7
    const int wm   = w >> 2;          // 0..1 : M-half
    const int wn   = w & 3;           // 0..3 : N-quarter (128 cols)
    const int b    = blockIdx.y;
    const int m0   = blockIdx.x * 128;  // pair-row tile (last block: 16 valid)

    // A-gen: 512 slots = 128 rows x 4 chunks of 8 cols; one slot per thread.
    const int rowA = tid >> 2, chA = tid & 3;
    int p = m0 + rowA; if (p >= kPairs) p = kPairs - 1;
    const int ia = p / 36, ja = p - ia * 36;
    const float* raP = ra + (size_t)(b * 36 + ia) * kD + chA * 8;
    const float* baP = ba + (size_t)(b * 36 + ia) * kD + chA * 8;
    const float* rbP = rb + (size_t)(b * 36 + ja) * kD + chA * 8;
    const float* bbP = bb + (size_t)(b * 36 + ja) * kD + chA * 8;

    const int fr = lane & 15, fq = lane >> 4;
    const int sr = lane >> 2, sc = (lane & 3) * 8;

    f32x4 acc[4][8];
    #pragma unroll
    for (int mt = 0; mt < 4; ++mt)
        #pragma unroll
        for (int nt = 0; nt < 8; ++nt)
            acc[mt][nt] = (f32x4)(0.f);

    if (tid < 128) scoreS[tid] = 0.f;

    float4 aL, aH, rL, rH, pL, pH, qL, qH;   // prefetched A-gen operands

    #define ISSUE_B(k0_, buf_)                                                   \
        _Pragma("unroll")                                                        \
        for (int t = 0; t < 4; ++t) {                                            \
            int r0 = w * 64 + t * 16;                                            \
            const unsigned short* gp = W0T + (size_t)(r0 + sr) * kD + (k0_) + sc;\
            __builtin_amdgcn_global_load_lds((glb_u32*)gp,                       \
                (lds_u32*)&Bs[buf_][r0][0], 16, 0, 0);                           \
        }

    #define LOAD_A(k0_)                                                          \
        aL = *(const float4*)(raP + (k0_));  aH = *(const float4*)(raP + (k0_) + 4); \
        rL = *(const float4*)(rbP + (k0_));  rH = *(const float4*)(rbP + (k0_) + 4); \
        pL = *(const float4*)(baP + (k0_));  pH = *(const float4*)(baP + (k0_) + 4); \
        qL = *(const float4*)(bbP + (k0_));  qH = *(const float4*)(bbP + (k0_) + 4);

    #define WRITE_REL()                                                          \
        {                                                                        \
            bf16x8 o;                                                            \
            o[0] = (short)f2bf(aL.x * rL.x + pL.x * qL.x);                       \
            o[1] = (short)f2bf(aL.y * rL.y + pL.y * qL.y);                       \
            o[2] = (short)f2bf(aL.z * rL.z + pL.z * qL.z);                       \
            o[3] = (short)f2bf(aL.w * rL.w + pL.w * qL.w);                       \
            o[4] = (short)f2bf(aH.x * rH.x + pH.x * qH.x);                       \
            o[5] = (short)f2bf(aH.y * rH.y + pH.y * qH.y);                       \
            o[6] = (short)f2bf(aH.z * rH.z + pH.z * qH.z);                       \
            o[7] = (short)f2bf(aH.w * rH.w + pH.w * qH.w);                       \
            *(bf16x8*)&RelS[rowA][chA * 8] = o;                                  \
        }

    // prologue
    ISSUE_B(0, 0)
    LOAD_A(0)

    for (int k0 = 0; k0 < kD; k0 += 32) {
        const int cur = (k0 >> 5) & 1, nxt = cur ^ 1;
        const bool more = (k0 + 32 < kD);
        __syncthreads();   // B1: Bs[cur] DMA + A-loads drained; prev af reads done
        WRITE_REL()
        __syncthreads();   // B2: RelS visible (only LDS writes outstanding -> cheap)
        if (more) {
            ISSUE_B(k0 + 32, nxt)   // in flight across this step's MFMA phase
            LOAD_A(k0 + 32)
        }
        bf16x8 af[4];
        #pragma unroll
        for (int mt = 0; mt < 4; ++mt)
            af[mt] = *(bf16x8*)&RelS[wm * 64 + mt * 16 + fr][fq * 8];
        #pragma unroll
        for (int nt = 0; nt < 8; ++nt) {
            bf16x8 bf = *(bf16x8*)&Bs[cur][wn * 128 + nt * 16 + fr][fq * 8];
            #pragma unroll
            for (int mt = 0; mt < 4; ++mt)
                acc[mt][nt] = __builtin_amdgcn_mfma_f32_16x16x32_bf16(af[mt], bf, acc[mt][nt], 0, 0, 0);
        }
    }

    // epilogue: score_row = sum_cols W1*tanh(H + b0); b1 softmax-invariant
    float b0v[8], w1v[8];
    #pragma unroll
    for (int nt = 0; nt < 8; ++nt) {
        int col = wn * 128 + nt * 16 + fr;
        b0v[nt] = b0[col];
        w1v[nt] = W1[col];
    }
    __syncthreads();
    #pragma unroll
    for (int mt = 0; mt < 4; ++mt) {
        #pragma unroll
        for (int reg = 0; reg < 4; ++reg) {
            float pv = 0.f;
            #pragma unroll
            for (int nt = 0; nt < 8; ++nt)
                pv += w1v[nt] * tanhf(acc[mt][nt][reg] + b0v[nt]);
            pv += __shfl_xor(pv, 1, 64);
            pv += __shfl_xor(pv, 2, 64);
            pv += __shfl_xor(pv, 4, 64);
            pv += __shfl_xor(pv, 8, 64);
            if (fr == 0)
                atomicAdd(&scoreS[wm * 64 + mt * 16 + fq * 4 + reg], pv);
        }
    }
    __syncthreads();
    if (tid < 128 && m0 + tid < kPairs)
        scores[(size_t)b * kPairs + m0 + tid] = scoreS[tid];
}

// ---------------------------------------------------------------------------
// K5: softmax over j
// ---------------------------------------------------------------------------
__global__ __launch_bounds__(64)
void k5_softmax(const float* __restrict__ scores, float* __restrict__ att)
{
    const int bi = blockIdx.x;
    const int tid = threadIdx.x;
    float s = (tid < kN) ? scores[(size_t)bi * kN + tid] : -1e30f;
    float m = s;
    #pragma unroll
    for (int off = 32; off >= 1; off >>= 1)
        m = fmaxf(m, __shfl_xor(m, off, 64));
    float e = (tid < kN) ? expf(s - m) : 0.f;
    float sum = e;
    #pragma unroll
    for (int off = 32; off >= 1; off >>= 1)
        sum += __shfl_xor(sum, off, 64);
    if (tid < kN) att[(size_t)bi * kN + tid] = e / sum;
}

// ---------------------------------------------------------------------------
// K6: out[b,i,:] = obj + fused + ra_i.(att_i @ RB_b) + ba_i.(att_i @ BB_b)
// ---------------------------------------------------------------------------
__global__ __launch_bounds__(256)
void k6_output(const float* __restrict__ obj, const unsigned short* __restrict__ fusedb,
               const float* __restrict__ ra, const float* __restrict__ ba,
               const float* __restrict__ rb, const float* __restrict__ bb,
               const float* __restrict__ att, float* __restrict__ out)
{
    __shared__ float attS[kN];
    const int bi = blockIdx.x;
    const int b = bi / kN;
    const int tid = threadIdx.x;
    if (tid < kN) attS[tid] = att[(size_t)bi * kN + tid];
    __syncthreads();
    for (int d = tid; d < kD; d += 256) {
        float s1 = 0.f, s2 = 0.f;
        #pragma unroll 4
        for (int j = 0; j < kN; ++j) {
            float a = attS[j];
            size_t rrow = (size_t)(b * kN + j) * kD + d;
            s1 = fmaf(a, rb[rrow], s1);
            s2 = fmaf(a, bb[rrow], s2);
        }
        size_t o = (size_t)bi * kD + d;
        float fv = __uint_as_float((u32)fusedb[o] << 16);
        out[o] = obj[o] + fv + ra[o] * s1 + ba[o] * s2;
    }
}

// ---------------------------------------------------------------------------
extern "C" void kernel_launch(void* const* d_in, const int* in_sizes, int n_in,
                              void* d_out, int out_size, void* d_ws, size_t ws_size,
                              hipStream_t stream)
{
    const float* q   = (const float*)d_in[0];
    const float* obj = (const float*)d_in[1];
    const float* box = (const float*)d_in[2];
    const float* Wq  = (const float*)d_in[3];
    const float* Wo  = (const float*)d_in[4];
    const float* Wfa = (const float*)d_in[5];
    const float* Wfb = (const float*)d_in[6];
    const float* Wba = (const float*)d_in[7];
    const float* Wbb = (const float*)d_in[8];
    const float* W0  = (const float*)d_in[9];
    const float* b0v = (const float*)d_in[10];
    const float* W1  = (const float*)d_in[11];
    // d_in[12] = b1 (softmax-invariant), d_in[13..14] scalars: unused
    float* out = (float*)d_out;

    const size_t nBD = (size_t)kBN * kD;
    float* ws = (float*)d_ws;
    size_t off = 0;
    float* ra     = ws + off; off += nBD;
    float* rb     = ws + off; off += nBD;
    float* ba     = ws + off; off += nBD;
    float* bb     = ws + off; off += nBD;
    float* scores = ws + off; off += (size_t)kBN * kN;
    float* att    = ws + off; off += (size_t)kBN * kN;

    unsigned short* us = (unsigned short*)(ws + off);
    size_t uoff = 0;
    unsigned short* W0T     = us + uoff; uoff += (size_t)kDatt * kD;
    unsigned short* q_bf    = us + uoff; uoff += nBD;
    unsigned short* obj_bf  = us + uoff; uoff += nBD;
    unsigned short* fusedbf = us + uoff; uoff += nBD;
    unsigned short* WqT     = us + uoff; uoff += (size_t)kD * kD;
    unsigned short* WoT     = us + uoff; uoff += (size_t)kD * kD;
    // WfaT/WfbT alias q_bf/obj_bf (dead after k1; stream order guarantees safety)
    unsigned short* WfaT = q_bf;
    unsigned short* WfbT = obj_bf;

    const int n4 = (int)(nBD / 4);
    kcvt<<<dim3((n4 + 255) / 256), 256, 0, stream>>>(q,   q_bf,   n4);
    kcvt<<<dim3((n4 + 255) / 256), 256, 0, stream>>>(obj, obj_bf, n4);
    ktrp<<<dim3(32, 32), 256, 0, stream>>>(Wq, WqT, kD);
    ktrp<<<dim3(32, 32), 256, 0, stream>>>(Wo, WoT, kD);
    ktrp<<<dim3(32, 8),  256, 0, stream>>>(W0, W0T, kDatt);
    k3_box_proj<<<dim3(kD / 256, kBN), 256, 0, stream>>>(box, Wba, Wbb, ba, bb);

    k1_dual_mfma<<<dim3(kD / 64, kBN / 128), 256, 0, stream>>>(q_bf, WqT, obj_bf, WoT, fusedbf);

    ktrp<<<dim3(32, 32), 256, 0, stream>>>(Wfa, WfaT, kD);
    ktrp<<<dim3(32, 32), 256, 0, stream>>>(Wfb, WfbT, kD);

    k2_dual_mfma<<<dim3(kD / 64, kBN / 128), 256, 0, stream>>>(fusedbf, WfaT, WfbT, ra, rb);

    k4_scores_mfma<<<dim3(11, kB), 512, 0, stream>>>(ra, rb, ba, bb, W0T, b0v, W1, scores);
    k5_softmax<<<kBN, 64, 0, stream>>>(scores, att);
    k6_output<<<kBN, 256, 0, stream>>>(obj, fusedbf, ra, ba, rb, bb, att, out);
}

// Round 7
// 955.082 us; speedup vs baseline: 3.3735x; 3.3735x over previous
//
#include <hip/hip_runtime.h>
#include <hip/hip_bf16.h>
#include <math.h>

constexpr int kB    = 64;
constexpr int kN    = 36;
constexpr int kBN   = kB * kN;   // 2304
constexpr int kD    = 2048;
constexpr int kDatt = 512;
constexpr int kPairs = kN * kN;  // 1296

using bf16x8 = __attribute__((ext_vector_type(8))) short;
using f32x4  = __attribute__((ext_vector_type(4))) float;

typedef unsigned int u32;
typedef __attribute__((address_space(3))) u32 lds_u32;
typedef const __attribute__((address_space(1))) u32 glb_u32;

__device__ inline unsigned short f2bf(float f) {
    union { float f; unsigned u; } v; v.f = f;
    unsigned r = v.u + 0x7FFFu + ((v.u >> 16) & 1u);   // RNE
    return (unsigned short)(r >> 16);
}

// ---------------------------------------------------------------------------
// kcvt: f32 -> bf16 elementwise
// ---------------------------------------------------------------------------
__global__ __launch_bounds__(256)
void kcvt(const float* __restrict__ x, unsigned short* __restrict__ y, int n4)
{
    int i = blockIdx.x * 256 + threadIdx.x;
    if (i < n4) {
        float4 v = ((const float4*)x)[i];
        ushort4 o = {f2bf(v.x), f2bf(v.y), f2bf(v.z), f2bf(v.w)};
        ((ushort4*)y)[i] = o;
    }
}

// ---------------------------------------------------------------------------
// ktrp: W[kD][nt] f32 -> WT[nt][kD] bf16 (transpose + convert)
// ---------------------------------------------------------------------------
__global__ __launch_bounds__(256)
void ktrp(const float* __restrict__ W, unsigned short* __restrict__ WT, int nt)
{
    __shared__ float T[64][65];
    const int k0 = blockIdx.x * 64;
    const int n0 = blockIdx.y * 64;
    const int c = threadIdx.x & 63, r0 = threadIdx.x >> 6;
    #pragma unroll
    for (int rr = 0; rr < 64; rr += 4)
        T[r0 + rr][c] = W[(size_t)(k0 + r0 + rr) * nt + n0 + c];
    __syncthreads();
    #pragma unroll
    for (int rr = 0; rr < 64; rr += 4)
        WT[(size_t)(n0 + r0 + rr) * kD + k0 + c] = f2bf(T[c][r0 + rr]);
}

// ---------------------------------------------------------------------------
// K3: ba/bb = box @ Wba/Wbb, K=4 -> elementwise
// ---------------------------------------------------------------------------
__global__ __launch_bounds__(256)
void k3_box_proj(const float* __restrict__ box, const float* __restrict__ Wba,
                 const float* __restrict__ Wbb,
                 float* __restrict__ ba, float* __restrict__ bb)
{
    const int r = blockIdx.y;
    const int c = blockIdx.x * 256 + threadIdx.x;
    const float x0 = box[r * 4 + 0], x1 = box[r * 4 + 1];
    const float x2 = box[r * 4 + 2], x3 = box[r * 4 + 3];
    float va = x0 * Wba[c] + x1 * Wba[kD + c] + x2 * Wba[2 * kD + c] + x3 * Wba[3 * kD + c];
    float vb = x0 * Wbb[c] + x1 * Wbb[kD + c] + x2 * Wbb[2 * kD + c] + x3 * Wbb[3 * kD + c];
    ba[(size_t)r * kD + c] = va;
    bb[(size_t)r * kD + c] = vb;
}

// ---------------------------------------------------------------------------
// Staging helpers for k1/k2: Rx32 bf16 tiles via global_load_lds width=16.
// ---------------------------------------------------------------------------
__device__ inline void stage128(const unsigned short* __restrict__ g,
                                int grow0, int k0,
                                unsigned short* lds, int w, int lane)
{
    const int sr = lane >> 2, sc = (lane & 3) * 8;
    #pragma unroll
    for (int t = 0; t < 2; ++t) {
        int r = w * 32 + t * 16;
        const unsigned short* gp = g + (size_t)(grow0 + r + sr) * kD + k0 + sc;
        __builtin_amdgcn_global_load_lds((glb_u32*)gp, (lds_u32*)(lds + r * 32), 16, 0, 0);
    }
}
__device__ inline void stage64(const unsigned short* __restrict__ g,
                               int grow0, int k0,
                               unsigned short* lds, int w, int lane)
{
    const int sr = lane >> 2, sc = (lane & 3) * 8;
    int r = w * 16;
    const unsigned short* gp = g + (size_t)(grow0 + r + sr) * kD + k0 + sc;
    __builtin_amdgcn_global_load_lds((glb_u32*)gp, (lds_u32*)(lds + r * 32), 16, 0, 0);
}

// ---------------------------------------------------------------------------
// K1 (MFMA dual): fused_bf16 = bf16((Qb @ WqT') .* (Ob @ WoT')), 128x64 tile
// ---------------------------------------------------------------------------
__global__ __launch_bounds__(256, 2)
void k1_dual_mfma(const unsigned short* __restrict__ Qb,
                  const unsigned short* __restrict__ WqT,
                  const unsigned short* __restrict__ Ob,
                  const unsigned short* __restrict__ WoT,
                  unsigned short* __restrict__ fusedb)
{
    __shared__ __align__(16) unsigned short As1[128][32];
    __shared__ __align__(16) unsigned short As2[128][32];
    __shared__ __align__(16) unsigned short Bs1[64][32];
    __shared__ __align__(16) unsigned short Bs2[64][32];

    const int tid = threadIdx.x;
    const int lane = tid & 63;
    const int w = tid >> 6;
    const int wm = w >> 1, wn = w & 1;
    const int row0 = blockIdx.y * 128;
    const int col0 = blockIdx.x * 64;

    f32x4 acc1[4][2], acc2[4][2];
    #pragma unroll
    for (int mt = 0; mt < 4; ++mt)
        #pragma unroll
        for (int nt = 0; nt < 2; ++nt) { acc1[mt][nt] = (f32x4)(0.f); acc2[mt][nt] = (f32x4)(0.f); }

    const int fr = lane & 15, ko = (lane >> 4) * 8;

    for (int k0 = 0; k0 < kD; k0 += 32) {
        stage128(Qb,  row0, k0, &As1[0][0], w, lane);
        stage128(Ob,  row0, k0, &As2[0][0], w, lane);
        stage64 (WqT, col0, k0, &Bs1[0][0], w, lane);
        stage64 (WoT, col0, k0, &Bs2[0][0], w, lane);
        __syncthreads();

        bf16x8 a1[4], a2[4];
        #pragma unroll
        for (int mt = 0; mt < 4; ++mt) {
            a1[mt] = *(bf16x8*)&As1[wm * 64 + mt * 16 + fr][ko];
            a2[mt] = *(bf16x8*)&As2[wm * 64 + mt * 16 + fr][ko];
        }
        #pragma unroll
        for (int nt = 0; nt < 2; ++nt) {
            bf16x8 b1 = *(bf16x8*)&Bs1[wn * 32 + nt * 16 + fr][ko];
            bf16x8 b2 = *(bf16x8*)&Bs2[wn * 32 + nt * 16 + fr][ko];
            #pragma unroll
            for (int mt = 0; mt < 4; ++mt) {
                acc1[mt][nt] = __builtin_amdgcn_mfma_f32_16x16x32_bf16(a1[mt], b1, acc1[mt][nt], 0, 0, 0);
                acc2[mt][nt] = __builtin_amdgcn_mfma_f32_16x16x32_bf16(a2[mt], b2, acc2[mt][nt], 0, 0, 0);
            }
        }
        __syncthreads();
    }

    const int fq = lane >> 4;
    #pragma unroll
    for (int mt = 0; mt < 4; ++mt)
        #pragma unroll
        for (int nt = 0; nt < 2; ++nt) {
            int row = row0 + wm * 64 + mt * 16 + fq * 4;
            int col = col0 + wn * 32 + nt * 16 + fr;
            #pragma unroll
            for (int reg = 0; reg < 4; ++reg) {
                float v = acc1[mt][nt][reg] * acc2[mt][nt][reg];
                fusedb[(size_t)(row + reg) * kD + col] = f2bf(v);
            }
        }
}

// ---------------------------------------------------------------------------
// K2 (MFMA dual-B): ra = Fb @ WfaT', rb = Fb @ WfbT', 128x64 tile
// ---------------------------------------------------------------------------
__global__ __launch_bounds__(256, 2)
void k2_dual_mfma(const unsigned short* __restrict__ Fb,
                  const unsigned short* __restrict__ WfaT,
                  const unsigned short* __restrict__ WfbT,
                  float* __restrict__ ra, float* __restrict__ rb)
{
    __shared__ __align__(16) unsigned short As [128][32];
    __shared__ __align__(16) unsigned short Bs1[64][32];
    __shared__ __align__(16) unsigned short Bs2[64][32];

    const int tid = threadIdx.x;
    const int lane = tid & 63;
    const int w = tid >> 6;
    const int wm = w >> 1, wn = w & 1;
    const int row0 = blockIdx.y * 128;
    const int col0 = blockIdx.x * 64;

    f32x4 acc1[4][2], acc2[4][2];
    #pragma unroll
    for (int mt = 0; mt < 4; ++mt)
        #pragma unroll
        for (int nt = 0; nt < 2; ++nt) { acc1[mt][nt] = (f32x4)(0.f); acc2[mt][nt] = (f32x4)(0.f); }

    const int fr = lane & 15, ko = (lane >> 4) * 8;

    for (int k0 = 0; k0 < kD; k0 += 32) {
        stage128(Fb,   row0, k0, &As [0][0], w, lane);
        stage64 (WfaT, col0, k0, &Bs1[0][0], w, lane);
        stage64 (WfbT, col0, k0, &Bs2[0][0], w, lane);
        __syncthreads();

        bf16x8 a[4];
        #pragma unroll
        for (int mt = 0; mt < 4; ++mt)
            a[mt] = *(bf16x8*)&As[wm * 64 + mt * 16 + fr][ko];
        #pragma unroll
        for (int nt = 0; nt < 2; ++nt) {
            bf16x8 b1 = *(bf16x8*)&Bs1[wn * 32 + nt * 16 + fr][ko];
            bf16x8 b2 = *(bf16x8*)&Bs2[wn * 32 + nt * 16 + fr][ko];
            #pragma unroll
            for (int mt = 0; mt < 4; ++mt) {
                acc1[mt][nt] = __builtin_amdgcn_mfma_f32_16x16x32_bf16(a[mt], b1, acc1[mt][nt], 0, 0, 0);
                acc2[mt][nt] = __builtin_amdgcn_mfma_f32_16x16x32_bf16(a[mt], b2, acc2[mt][nt], 0, 0, 0);
            }
        }
        __syncthreads();
    }

    const int fq = lane >> 4;
    #pragma unroll
    for (int mt = 0; mt < 4; ++mt)
        #pragma unroll
        for (int nt = 0; nt < 2; ++nt) {
            int row = row0 + wm * 64 + mt * 16 + fq * 4;
            int col = col0 + wn * 32 + nt * 16 + fr;
            #pragma unroll
            for (int reg = 0; reg < 4; ++reg) {
                size_t o = (size_t)(row + reg) * kD + col;
                ra[o] = acc1[mt][nt][reg];
                rb[o] = acc2[mt][nt][reg];
            }
        }
}

// ---------------------------------------------------------------------------
// K4 v5: no B-LDS. B-frags loaded per-wave directly from L2-resident W0T
// (each Bs row was read by exactly one wave -> LDS staging had zero reuse;
// it only cost DMA + 8-way bank conflicts). RelS (real x4 reuse) stays in
// LDS, single-buffered, padded to 36 shorts (18-dword stride -> 2-way=free).
// launch_bounds(512,2): NEVER request 4 waves/SIMD here - acc=128 regs,
// unified VGPR/AGPR file -> (512,4) forces the accumulator to spill to
// scratch (R5: 10.5 GB HBM traffic, 7.5x regression).
// ---------------------------------------------------------------------------
__global__ __launch_bounds__(512, 2)
void k4_scores_mfma(const float* __restrict__ ra, const float* __restrict__ rb,
                    const float* __restrict__ ba, const float* __restrict__ bb,
                    const unsigned short* __restrict__ W0T,
                    const float* __restrict__ b0, const float* __restrict__ W1,
                    float* __restrict__ scores)
{
    __shared__ __align__(16) unsigned short RelS[128][36];    // 9 KB, 2-way max
    __shared__ float scoreS[128];

    const int tid  = threadIdx.x;
    const int lane = tid & 63;
    const int w    = tid >> 6;        // 0..7
    const int wm   = w >> 2;          // 0..1 : M-half
    const int wn   = w & 3;           // 0..3 : N-quarter (128 cols)
    const int b    = blockIdx.y;
    const int m0   = blockIdx.x * 128;  // pair-row tile (last block: 16 valid)

    // A-gen: 512 slots = 128 rows x 4 chunks of 8 cols; one slot per thread.
    const int rowA = tid >> 2, chA = tid & 3;
    int p = m0 + rowA; if (p >= kPairs) p = kPairs - 1;
    const int ia = p / 36, ja = p - ia * 36;
    const float* raP = ra + (size_t)(b * 36 + ia) * kD + chA * 8;
    const float* baP = ba + (size_t)(b * 36 + ia) * kD + chA * 8;
    const float* rbP = rb + (size_t)(b * 36 + ja) * kD + chA * 8;
    const float* bbP = bb + (size_t)(b * 36 + ja) * kD + chA * 8;

    const int fr = lane & 15, fq = lane >> 4;
    const unsigned short* W0Twave = W0T + (size_t)(wn * 128 + fr) * kD + fq * 8;

    f32x4 acc[4][8];
    #pragma unroll
    for (int mt = 0; mt < 4; ++mt)
        #pragma unroll
        for (int nt = 0; nt < 8; ++nt)
            acc[mt][nt] = (f32x4)(0.f);

    if (tid < 128) scoreS[tid] = 0.f;

    float4 aL, aH, rL, rH, pL, pH, qL, qH;   // prefetched A-gen operands

    #define LOAD_A(k0_)                                                          \
        aL = *(const float4*)(raP + (k0_));  aH = *(const float4*)(raP + (k0_) + 4); \
        rL = *(const float4*)(rbP + (k0_));  rH = *(const float4*)(rbP + (k0_) + 4); \
        pL = *(const float4*)(baP + (k0_));  pH = *(const float4*)(baP + (k0_) + 4); \
        qL = *(const float4*)(bbP + (k0_));  qH = *(const float4*)(bbP + (k0_) + 4);

    #define WRITE_REL()                                                          \
        {                                                                        \
            bf16x8 o;                                                            \
            o[0] = (short)f2bf(aL.x * rL.x + pL.x * qL.x);                       \
            o[1] = (short)f2bf(aL.y * rL.y + pL.y * qL.y);                       \
            o[2] = (short)f2bf(aL.z * rL.z + pL.z * qL.z);                       \
            o[3] = (short)f2bf(aL.w * rL.w + pL.w * qL.w);                       \
            o[4] = (short)f2bf(aH.x * rH.x + pH.x * qH.x);                       \
            o[5] = (short)f2bf(aH.y * rH.y + pH.y * qH.y);                       \
            o[6] = (short)f2bf(aH.z * rH.z + pH.z * qH.z);                       \
            o[7] = (short)f2bf(aH.w * rH.w + pH.w * qH.w);                       \
            *(bf16x8*)&RelS[rowA][chA * 8] = o;                                  \
        }

    // prologue
    LOAD_A(0)

    for (int k0 = 0; k0 < kD; k0 += 32) {
        const bool more = (k0 + 32 < kD);
        __syncthreads();   // B1: prior step's af reads done -> safe to overwrite RelS
        WRITE_REL()
        __syncthreads();   // B2: RelS visible
        if (more) { LOAD_A(k0 + 32) }   // A-prefetch flies across MFMA phase

        bf16x8 af[4];
        #pragma unroll
        for (int mt = 0; mt < 4; ++mt)
            af[mt] = *(bf16x8*)&RelS[wm * 64 + mt * 16 + fr][fq * 8];
        #pragma unroll
        for (int nt = 0; nt < 8; ++nt) {
            bf16x8 bf = *(const bf16x8*)(W0Twave + (size_t)(nt * 16) * kD + k0);
            #pragma unroll
            for (int mt = 0; mt < 4; ++mt)
                acc[mt][nt] = __builtin_amdgcn_mfma_f32_16x16x32_bf16(af[mt], bf, acc[mt][nt], 0, 0, 0);
        }
    }

    // epilogue: score_row = sum_cols W1*tanh(H + b0); b1 softmax-invariant
    float b0v[8], w1v[8];
    #pragma unroll
    for (int nt = 0; nt < 8; ++nt) {
        int col = wn * 128 + nt * 16 + fr;
        b0v[nt] = b0[col];
        w1v[nt] = W1[col];
    }
    __syncthreads();
    #pragma unroll
    for (int mt = 0; mt < 4; ++mt) {
        #pragma unroll
        for (int reg = 0; reg < 4; ++reg) {
            float pv = 0.f;
            #pragma unroll
            for (int nt = 0; nt < 8; ++nt)
                pv += w1v[nt] * tanhf(acc[mt][nt][reg] + b0v[nt]);
            pv += __shfl_xor(pv, 1, 64);
            pv += __shfl_xor(pv, 2, 64);
            pv += __shfl_xor(pv, 4, 64);
            pv += __shfl_xor(pv, 8, 64);
            if (fr == 0)
                atomicAdd(&scoreS[wm * 64 + mt * 16 + fq * 4 + reg], pv);
        }
    }
    __syncthreads();
    if (tid < 128 && m0 + tid < kPairs)
        scores[(size_t)b * kPairs + m0 + tid] = scoreS[tid];
}

// ---------------------------------------------------------------------------
// K5: softmax over j
// ---------------------------------------------------------------------------
__global__ __launch_bounds__(64)
void k5_softmax(const float* __restrict__ scores, float* __restrict__ att)
{
    const int bi = blockIdx.x;
    const int tid = threadIdx.x;
    float s = (tid < kN) ? scores[(size_t)bi * kN + tid] : -1e30f;
    float m = s;
    #pragma unroll
    for (int off = 32; off >= 1; off >>= 1)
        m = fmaxf(m, __shfl_xor(m, off, 64));
    float e = (tid < kN) ? expf(s - m) : 0.f;
    float sum = e;
    #pragma unroll
    for (int off = 32; off >= 1; off >>= 1)
        sum += __shfl_xor(sum, off, 64);
    if (tid < kN) att[(size_t)bi * kN + tid] = e / sum;
}

// ---------------------------------------------------------------------------
// K6: out[b,i,:] = obj + fused + ra_i.(att_i @ RB_b) + ba_i.(att_i @ BB_b)
// ---------------------------------------------------------------------------
__global__ __launch_bounds__(256)
void k6_output(const float* __restrict__ obj, const unsigned short* __restrict__ fusedb,
               const float* __restrict__ ra, const float* __restrict__ ba,
               const float* __restrict__ rb, const float* __restrict__ bb,
               const float* __restrict__ att, float* __restrict__ out)
{
    __shared__ float attS[kN];
    const int bi = blockIdx.x;
    const int b = bi / kN;
    const int tid = threadIdx.x;
    if (tid < kN) attS[tid] = att[(size_t)bi * kN + tid];
    __syncthreads();
    for (int d = tid; d < kD; d += 256) {
        float s1 = 0.f, s2 = 0.f;
        #pragma unroll 4
        for (int j = 0; j < kN; ++j) {
            float a = attS[j];
            size_t rrow = (size_t)(b * kN + j) * kD + d;
            s1 = fmaf(a, rb[rrow], s1);
            s2 = fmaf(a, bb[rrow], s2);
        }
        size_t o = (size_t)bi * kD + d;
        float fv = __uint_as_float((u32)fusedb[o] << 16);
        out[o] = obj[o] + fv + ra[o] * s1 + ba[o] * s2;
    }
}

// ---------------------------------------------------------------------------
extern "C" void kernel_launch(void* const* d_in, const int* in_sizes, int n_in,
                              void* d_out, int out_size, void* d_ws, size_t ws_size,
                              hipStream_t stream)
{
    const float* q   = (const float*)d_in[0];
    const float* obj = (const float*)d_in[1];
    const float* box = (const float*)d_in[2];
    const float* Wq  = (const float*)d_in[3];
    const float* Wo  = (const float*)d_in[4];
    const float* Wfa = (const float*)d_in[5];
    const float* Wfb = (const float*)d_in[6];
    const float* Wba = (const float*)d_in[7];
    const float* Wbb = (const float*)d_in[8];
    const float* W0  = (const float*)d_in[9];
    const float* b0v = (const float*)d_in[10];
    const float* W1  = (const float*)d_in[11];
    // d_in[12] = b1 (softmax-invariant), d_in[13..14] scalars: unused
    float* out = (float*)d_out;

    const size_t nBD = (size_t)kBN * kD;
    float* ws = (float*)d_ws;
    size_t off = 0;
    float* ra     = ws + off; off += nBD;
    float* rb     = ws + off; off += nBD;
    float* ba     = ws + off; off += nBD;
    float* bb     = ws + off; off += nBD;
    float* scores = ws + off; off += (size_t)kBN * kN;
    float* att    = ws + off; off += (size_t)kBN * kN;

    unsigned short* us = (unsigned short*)(ws + off);
    size_t uoff = 0;
    unsigned short* W0T     = us + uoff; uoff += (size_t)kDatt * kD;
    unsigned short* q_bf    = us + uoff; uoff += nBD;
    unsigned short* obj_bf  = us + uoff; uoff += nBD;
    unsigned short* fusedbf = us + uoff; uoff += nBD;
    unsigned short* WqT     = us + uoff; uoff += (size_t)kD * kD;
    unsigned short* WoT     = us + uoff; uoff += (size_t)kD * kD;
    // WfaT/WfbT alias q_bf/obj_bf (dead after k1; stream order guarantees safety)
    unsigned short* WfaT = q_bf;
    unsigned short* WfbT = obj_bf;

    const int n4 = (int)(nBD / 4);
    kcvt<<<dim3((n4 + 255) / 256), 256, 0, stream>>>(q,   q_bf,   n4);
    kcvt<<<dim3((n4 + 255) / 256), 256, 0, stream>>>(obj, obj_bf, n4);
    ktrp<<<dim3(32, 32), 256, 0, stream>>>(Wq, WqT, kD);
    ktrp<<<dim3(32, 32), 256, 0, stream>>>(Wo, WoT, kD);
    ktrp<<<dim3(32, 8),  256, 0, stream>>>(W0, W0T, kDatt);
    k3_box_proj<<<dim3(kD / 256, kBN), 256, 0, stream>>>(box, Wba, Wbb, ba, bb);

    k1_dual_mfma<<<dim3(kD / 64, kBN / 128), 256, 0, stream>>>(q_bf, WqT, obj_bf, WoT, fusedbf);

    ktrp<<<dim3(32, 32), 256, 0, stream>>>(Wfa, WfaT, kD);
    ktrp<<<dim3(32, 32), 256, 0, stream>>>(Wfb, WfbT, kD);

    k2_dual_mfma<<<dim3(kD / 64, kBN / 128), 256, 0, stream>>>(fusedbf, WfaT, WfbT, ra, rb);

    k4_scores_mfma<<<dim3(11, kB), 512, 0, stream>>>(ra, rb, ba, bb, W0T, b0v, W1, scores);
    k5_softmax<<<kBN, 64, 0, stream>>>(scores, att);
    k6_output<<<kBN, 256, 0, stream>>>(obj, fusedbf, ra, ba, rb, bb, att, out);
}